// Round 1
// baseline (49.973 us; speedup 1.0000x reference)
//
#include <hip/hip_runtime.h>
#include <math.h>

// Problem constants (setup_inputs is fixed: B=64, T=512, H=768, L=400)
namespace {
constexpr int kB  = 64;
constexpr int kT  = 512;
constexpr int kH  = 768;
constexpr int kHm = 767;   // H-1 feature channels
constexpr int kL  = 400;   // max_label_length
}

__device__ __forceinline__ float sigmoidf_(float x) {
  return 1.0f / (1.0f + expf(-x));
}

// One block per batch element b (512 threads):
//  - compute sigmoid of the alpha channel for all T steps (parallel)
//  - block-reduce alpha_sum, store to ws
//  - lane 0 runs the 400-step scalar recurrence from LDS, emitting
//    (w, m, sel) per k:  out_k = s + w*x ;  s_new = sel*s + m*x
__global__ __launch_bounds__(512) void k_rec(
    const float* __restrict__ hs, const int* __restrict__ labels,
    float* __restrict__ asum_ws, float4* __restrict__ wms) {
  __shared__ float a_lds[kT];
  __shared__ float red[kT];
  const int b = blockIdx.x;
  const int tid = threadIdx.x;

  float sig = sigmoidf_(hs[(size_t)b * kT * kH + (size_t)tid * kH + kHm]);
  a_lds[tid] = sig;
  red[tid] = sig;
  __syncthreads();
  for (int off = 256; off > 0; off >>= 1) {
    if (tid < off) red[tid] += red[tid + off];
    __syncthreads();
  }

  if (tid == 0) {
    const float as = red[0];
    asum_ws[b] = as;
    const int lab = labels[b];
    const float len = (float)(lab < kL ? lab : kL);
    const float scale = len / as;
    float a_r = 0.0f;
    float4* wb = wms + b * kL;
#pragma unroll 8
    for (int k = 0; k < kL; ++k) {
      const float ak = a_lds[k] * scale;
      const float a_a = ak + a_r;
      const bool fired = (a_a >= 1.0f);
      const float w   = fired ? (1.0f - a_r) : ak;
      const float arn = fired ? (ak - (1.0f - a_r)) : a_a;  // exact ref expr
      const float m   = fired ? arn : ak;
      const float sel = fired ? 0.0f : 1.0f;
      wb[k] = make_float4(w, m, sel, 0.0f);
      a_r = arn;
    }
  }
}

// Streaming scan: grid (ceil(767/256), B), 256 threads. Each thread owns one
// feature channel h of batch b and walks k = 0..399 sequentially.
// Per-k scalars are staged in LDS (uniform-address broadcast reads).
__global__ __launch_bounds__(256) void k_scan(
    const float* __restrict__ hs, const int* __restrict__ labels,
    const float* __restrict__ asum_ws, const float4* __restrict__ wms,
    float* __restrict__ out) {
  __shared__ float4 lw[kL];
  const int b = blockIdx.y;
  const int tid = threadIdx.x;

  for (int i = tid; i < kL; i += 256) lw[i] = wms[b * kL + i];
  __syncthreads();

  // n_hat = sum_b (len_b - alpha_sum_b)^2, done once by block (0,0)
  if (blockIdx.x == 0 && b == 0 && tid < kB) {
    const float as = asum_ws[tid];
    const int lab = labels[tid];
    const float len = (float)(lab < kL ? lab : kL);
    float d = len - as;
    float v = d * d;
    for (int off = 32; off > 0; off >>= 1) v += __shfl_down(v, off, 64);
    if (tid == 0) out[(size_t)kB * kL * kHm] = v;
  }

  const int h = blockIdx.x * 256 + tid;
  if (h >= kHm) return;

  const float* __restrict__ px = hs + (size_t)b * kT * kH + h;
  float* __restrict__ po = out + (size_t)b * kL * kHm + h;
  float s = 0.0f;
#pragma unroll 8
  for (int k = 0; k < kL; ++k) {
    const float x = px[(size_t)k * kH];
    const float4 c = lw[k];
    const float o = fmaf(c.x, x, s);
    po[(size_t)k * kHm] = o;
    s = fmaf(c.y, x, c.z * s);
  }
}

extern "C" void kernel_launch(void* const* d_in, const int* in_sizes, int n_in,
                              void* d_out, int out_size, void* d_ws, size_t ws_size,
                              hipStream_t stream) {
  const float* hs     = (const float*)d_in[0];
  const int*   labels = (const int*)d_in[1];
  float* out = (float*)d_out;

  // ws layout: [0,256B) alpha_sum (64 floats, padded); then (w,m,sel,_) float4
  // per (b,k): 64*400*16 B. Total ≈ 410 KB.
  float*  asum_ws = (float*)d_ws;
  float4* wms     = (float4*)((char*)d_ws + 256);

  k_rec<<<kB, 512, 0, stream>>>(hs, labels, asum_ws, wms);
  k_scan<<<dim3((kHm + 255) / 256, kB), 256, 0, stream>>>(hs, labels, asum_ws,
                                                          wms, out);
}

// Round 2
// 47.471 us; speedup vs baseline: 1.0527x; 1.0527x over previous
//
#include <hip/hip_runtime.h>
#include <math.h>

// Problem constants (setup_inputs is fixed: B=64, T=512, H=768, L=400)
namespace {
constexpr int kB  = 64;
constexpr int kT  = 512;
constexpr int kH  = 768;
constexpr int kHm = 767;   // H-1 feature channels
constexpr int kL  = 400;   // max_label_length
constexpr int kBK = 40;    // k-batch size for register double-buffering (400 = 10*40)
}

__device__ __forceinline__ float sigmoidf_(float x) {
  return 1.0f / (1.0f + expf(-x));
}

// One block per batch element b (512 threads):
//  - compute sigmoid of the alpha channel for all T steps (parallel)
//  - block-reduce alpha_sum, store to ws
//  - lane 0 runs the 400-step scalar recurrence from LDS, emitting
//    (w, m, sel) per k:  out_k = s + w*x ;  s_new = sel*s + m*x
__global__ __launch_bounds__(512) void k_rec(
    const float* __restrict__ hs, const int* __restrict__ labels,
    float* __restrict__ asum_ws, float4* __restrict__ wms) {
  __shared__ float a_lds[kT];
  __shared__ float red[kT];
  const int b = blockIdx.x;
  const int tid = threadIdx.x;

  float sig = sigmoidf_(hs[(size_t)b * kT * kH + (size_t)tid * kH + kHm]);
  a_lds[tid] = sig;
  red[tid] = sig;
  __syncthreads();
  for (int off = 256; off > 0; off >>= 1) {
    if (tid < off) red[tid] += red[tid + off];
    __syncthreads();
  }

  if (tid == 0) {
    const float as = red[0];
    asum_ws[b] = as;
    const int lab = labels[b];
    const float len = (float)(lab < kL ? lab : kL);
    const float scale = len / as;
    float a_r = 0.0f;
    float4* wb = wms + b * kL;
#pragma unroll 16
    for (int k = 0; k < kL; ++k) {
      const float ak = a_lds[k] * scale;
      const float a_a = ak + a_r;
      const bool fired = (a_a >= 1.0f);
      const float w   = fired ? (1.0f - a_r) : ak;
      const float arn = fired ? (ak - (1.0f - a_r)) : a_a;  // exact ref expr
      const float m   = fired ? arn : ak;
      const float sel = fired ? 0.0f : 1.0f;
      wb[k] = make_float4(w, m, sel, 0.0f);
      a_r = arn;
    }
  }
}

// Load BK consecutive k-steps of one channel into registers (independent loads,
// all indices compile-time so the array stays in VGPRs).
__device__ __forceinline__ void load_blk(const float* __restrict__ px, int k0,
                                         float (&x)[kBK]) {
#pragma unroll
  for (int i = 0; i < kBK; ++i) x[i] = px[(size_t)(k0 + i) * kH];
}

__device__ __forceinline__ void comp_blk(const float4* __restrict__ lw,
                                         float* __restrict__ po, int k0,
                                         const float (&x)[kBK], float& s) {
#pragma unroll
  for (int i = 0; i < kBK; ++i) {
    const float4 c = lw[k0 + i];
    const float o = fmaf(c.x, x[i], s);
    po[(size_t)(k0 + i) * kHm] = o;
    s = fmaf(c.y, x[i], c.z * s);
  }
}

// Streaming scan: grid (ceil(767/256), B), 256 threads. Each thread owns one
// feature channel h of batch b and walks k = 0..399 sequentially with
// register double-buffered prefetch (BK=40 deep) to keep ~8 MB of loads in
// flight device-wide (Little's law: need ~5.7 MB for 6.3 TB/s @ 900 ns).
__global__ __launch_bounds__(256) void k_scan(
    const float* __restrict__ hs, const int* __restrict__ labels,
    const float* __restrict__ asum_ws, const float4* __restrict__ wms,
    float* __restrict__ out) {
  __shared__ float4 lw[kL];
  const int b = blockIdx.y;
  const int tid = threadIdx.x;

  for (int i = tid; i < kL; i += 256) lw[i] = wms[b * kL + i];
  __syncthreads();

  // n_hat = sum_b (len_b - alpha_sum_b)^2, done once by block (0,0)
  if (blockIdx.x == 0 && b == 0 && tid < kB) {
    const float as = asum_ws[tid];
    const int lab = labels[tid];
    const float len = (float)(lab < kL ? lab : kL);
    float d = len - as;
    float v = d * d;
    for (int off = 32; off > 0; off >>= 1) v += __shfl_down(v, off, 64);
    if (tid == 0) out[(size_t)kB * kL * kHm] = v;
  }

  const int h = blockIdx.x * 256 + tid;
  if (h >= kHm) return;

  const float* __restrict__ px = hs + (size_t)b * kT * kH + h;
  float* __restrict__ po = out + (size_t)b * kL * kHm + h;

  float xa[kBK], xb[kBK];
  float s = 0.0f;
  load_blk(px, 0, xa);
  // 400/40 = 10 blocks, processed as 5 pairs with named double buffers
  for (int sb = 0; sb < 5; ++sb) {
    const int k0 = sb * 2 * kBK;
    load_blk(px, k0 + kBK, xb);        // prefetch next block
    comp_blk(lw, po, k0, xa, s);       // compute current (waits only on xa)
    if (sb < 4) load_blk(px, k0 + 2 * kBK, xa);
    comp_blk(lw, po, k0 + kBK, xb, s);
  }
}

extern "C" void kernel_launch(void* const* d_in, const int* in_sizes, int n_in,
                              void* d_out, int out_size, void* d_ws, size_t ws_size,
                              hipStream_t stream) {
  const float* hs     = (const float*)d_in[0];
  const int*   labels = (const int*)d_in[1];
  float* out = (float*)d_out;

  // ws layout: [0,256B) alpha_sum (64 floats, padded); then (w,m,sel,_) float4
  // per (b,k): 64*400*16 B. Total ≈ 410 KB.
  float*  asum_ws = (float*)d_ws;
  float4* wms     = (float4*)((char*)d_ws + 256);

  k_rec<<<kB, 512, 0, stream>>>(hs, labels, asum_ws, wms);
  k_scan<<<dim3((kHm + 255) / 256, kB), 256, 0, stream>>>(hs, labels, asum_ws,
                                                          wms, out);
}